// Round 6
// baseline (48.375 us; speedup 1.0000x reference)
//
#include <hip/hip_runtime.h>

typedef unsigned long long u64;

#define BATCH 64
#define CH    64
#define HH    56
#define WW    56
#define HW    3136
#define NBAND 14          // 56/4 rows per band
#define NBLK  (BATCH * NBAND)   // 896 = 8*112

// Kernel 1 (tiny): per-p weight fold. wbits in [p][10] layout (padded for 16B).
__global__ __launch_bounds__(256)
void fold_kernel(const float* __restrict__ w,
                 const float* __restrict__ gamma,
                 const float* __restrict__ beta,
                 const float* __restrict__ rmean,
                 const float* __restrict__ rvar,
                 const float* __restrict__ bias1,
                 const float* __restrict__ alpha,
                 const float* __restrict__ bias2,
                 u64* __restrict__ wbits,      // [64][10]
                 float* __restrict__ kc,       // [wc][lc][64]
                 float4* __restrict__ c4) {    // [64] {-2am, al, b2, 0}
    __shared__ float red[4];
    const int tid = threadIdx.x;
    const int lane = tid & 63;
    const int wv = tid >> 6;
    const int p = blockIdx.x;
    const float* wp = w + p * 576;

    float s = 0.f;
    for (int i = tid; i < 576; i += 256) s += fabsf(wp[i]);
#pragma unroll
    for (int off = 32; off > 0; off >>= 1) s += __shfl_down(s, off);
    if (lane == 0) red[wv] = s;
    __syncthreads();

    u64 m[9];
    if (wv == 0) {
#pragma unroll
        for (int t = 0; t < 9; ++t) {
            m[t] = __ballot(wp[lane * 9 + t] > 0.f);   // bit c = sign(w[p][c][t])
            if (lane == 0) wbits[p * 10 + t] = m[t];
        }
        if (lane == 0) wbits[p * 10 + 9] = 0;
    }
    if (tid == 0) {
        float scale = (red[0] + red[1] + red[2] + red[3]) * (1.0f / 576.0f);
        float inv = gamma[p] * rsqrtf(rvar[p] + 1e-5f);
        float am = scale * inv;
        float bd = beta[p] - rmean[p] * inv + bias1[p];
        float pt[9];
#pragma unroll
        for (int t = 0; t < 9; ++t) pt[t] = (float)__popcll(m[t]);
        const float cL = pt[0] + pt[3] + pt[6];   // dw=-1 column
        const float cR = pt[2] + pt[5] + pt[8];   // dw=+1 column
        const float rT = pt[0] + pt[1] + pt[2];   // dh=-1 row
        const float rB = pt[6] + pt[7] + pt[8];   // dh=+1 row
        float Ci[3][3] = {
            {0.f, cL,                 cR},
            {rT,  rT + pt[3] + pt[6], rT + pt[5] + pt[8]},
            {rB,  rB + pt[0] + pt[3], rB + pt[2] + pt[5]}};
        float nv[3][3] = {{9, 6, 6}, {6, 4, 4}, {6, 4, 4}};
#pragma unroll
        for (int wc = 0; wc < 3; ++wc)
#pragma unroll
            for (int lc = 0; lc < 3; ++lc)
                kc[wc * 192 + lc * 64 + p] =
                    fmaf(am, 64.f * nv[wc][lc] + 2.f * Ci[wc][lc], bd);
        c4[p] = make_float4(-2.f * am, alpha[p], bias2[p], 0.f);
    }
}

// Kernel 2: fused sign-pack + XNOR-popcount conv + BN/residual/PReLU epilogue.
// Block = 512 thr (8 waves) = one (b, 4-row band).
//   Phase 1: waves 0..5 ballot-pack image rows r0-1..r0+4 into Lsgn[6][58]
//            (zero-padded cols; invalid rows = 0) — boundary handled by kc.
//   Phase 2: wave (wv&3, wv>>2) = output row r0+(wv&3), channels (wv>>2)*32..+31.
__global__ __launch_bounds__(512, 6)
void fused_kernel(const float* __restrict__ x,
                  const float* __restrict__ bias0,
                  const u64* __restrict__ wbits,
                  const float* __restrict__ kc,
                  const float4* __restrict__ c4,
                  float* __restrict__ out) {
    __shared__ __align__(16) u64 Lsgn[6][58];
    __shared__ __align__(16) u64 wsm[64 * 10];
    __shared__ float kcsm[576];
    __shared__ float4 c4sm[64];

    const int tid = threadIdx.x;
    const int lane = tid & 63;
    const int wv = tid >> 6;

    // stage constant tables
    for (int i = tid; i < 640; i += 512) wsm[i] = wbits[i];
    for (int i = tid; i < 576; i += 512) kcsm[i] = kc[i];
    if (tid < 64) c4sm[tid] = c4[tid];

    // bijective XCD swizzle: 896 = 8 * 112 (consecutive wg share halo rows in L2)
    const int bid = blockIdx.x;
    const int wg = (bid & 7) * 112 + (bid >> 3);
    const int b = wg / NBAND;
    const int band = wg - b * NBAND;
    const int r0 = band * 4;

    // ---- Phase 1: pack 6 sign rows (lane = channel, ballot per w) ----
    if (wv < 6) {
        const int ir = r0 - 1 + wv;
        const bool rowok = (unsigned)ir < (unsigned)HH;
        u64 mine = 0;
        if (rowok) {
            const float* xp = x + ((size_t)(b * CH + lane)) * HW + ir * WW;
            const float bz = bias0[lane];
#pragma unroll
            for (int q = 0; q < 14; ++q) {
                float4 v = *(const float4*)(xp + q * 4);
                u64 m0 = __ballot(v.x + bz > 0.f);
                u64 m1 = __ballot(v.y + bz > 0.f);
                u64 m2 = __ballot(v.z + bz > 0.f);
                u64 m3 = __ballot(v.w + bz > 0.f);
                mine = (lane == q * 4 + 0) ? m0 : mine;
                mine = (lane == q * 4 + 1) ? m1 : mine;
                mine = (lane == q * 4 + 2) ? m2 : mine;
                mine = (lane == q * 4 + 3) ? m3 : mine;
            }
        }
        if (lane < WW) Lsgn[wv][1 + lane] = mine;
        else if (lane == 56) Lsgn[wv][0] = 0;
        else if (lane == 57) Lsgn[wv][57] = 0;
    }
    __syncthreads();

    // ---- Phase 2: XNOR-popcount conv ----
    const int rl = wv & 3;            // output row within band
    const int ph = (wv >> 2) << 5;    // channel half: 0 or 32
    const int h = r0 + rl;
    const int wcol = min(lane, WW - 1);
    const bool active = lane < WW;

    u64 a[9];
#pragma unroll
    for (int t = 0; t < 9; ++t)
        a[t] = Lsgn[rl + t / 3][wcol + t % 3];   // zero pads make this unconditional

    const int wclass = (h == 0) ? 1 : (h == HH - 1) ? 2 : 0;
    const int lclass = (wcol == 0) ? 1 : (lane == WW - 1) ? 2 : 0;
    const float* kp = kcsm + wclass * 192 + lclass * 64;

    const size_t xbase = (size_t)b * CH * HW + (size_t)h * WW + wcol;

#pragma unroll 4
    for (int i = 0; i < 32; ++i) {
        const int p = ph + i;
        const u64* wp = wsm + p * 10;
        unsigned int P = 0;
#pragma unroll
        for (int t = 0; t < 9; ++t) {
            u64 v = a[t] ^ wp[t];
            P += __popc((unsigned int)v);
            P += __popc((unsigned int)(v >> 32));
        }
        const float4 cc = c4sm[p];
        const float k = kp[p];
        const size_t off = xbase + (size_t)p * HW;
        const float res = x[off];
        float v = fmaf(cc.x, (float)P, k) + res;
        v = v >= 0.f ? v : cc.y * v;
        v += cc.z;
        if (active) out[off] = v;
    }
}

extern "C" void kernel_launch(void* const* d_in, const int* in_sizes, int n_in,
                              void* d_out, int out_size, void* d_ws, size_t ws_size,
                              hipStream_t stream) {
    const float* x     = (const float*)d_in[0];
    const float* bias0 = (const float*)d_in[1];
    const float* w     = (const float*)d_in[2];
    const float* gamma = (const float*)d_in[3];
    const float* beta  = (const float*)d_in[4];
    const float* rmean = (const float*)d_in[5];
    const float* rvar  = (const float*)d_in[6];
    const float* bias1 = (const float*)d_in[7];
    const float* alpha = (const float*)d_in[8];
    const float* bias2 = (const float*)d_in[9];
    float* out = (float*)d_out;

    char* ws = (char*)d_ws;
    u64* wbits = (u64*)ws;                 // 5,120 B
    float* kc  = (float*)(ws + 5120);      // 2,304 B
    float4* c4 = (float4*)(ws + 8192);     // 1,024 B

    fold_kernel<<<64, 256, 0, stream>>>(
        w, gamma, beta, rmean, rvar, bias1, alpha, bias2, wbits, kc, c4);

    fused_kernel<<<NBLK, 512, 0, stream>>>(x, bias0, wbits, kc, c4, out);
}

// Round 7
// 44.221 us; speedup vs baseline: 1.0939x; 1.0939x over previous
//
#include <hip/hip_runtime.h>

typedef unsigned long long u64;
typedef unsigned int u32;

#define BATCH 64
#define CH    64
#define HH    56
#define WW    56
#define HW    3136
#define SROW  64            // padded Spk row stride (u64 units)
#define SIMG  (58 * SROW)   // per-image u64 count (58 rows)
#define PBLK  896           // pack blocks (4 rows each)

// Kernel 1: pack sign bits into zero-padded [b][58][64] layout + weight/BN fold.
//  blk < PBLK : 4 rows, one per wave; lane = channel; ballot-pack; write row + col pads.
//  blk >= PBLK: p = blk-PBLK. wtab record (9 w-words + consts) + kc class table.
__global__ __launch_bounds__(256)
void pack_kernel(const float* __restrict__ x,
                 const float* __restrict__ bias0,
                 const float* __restrict__ w,
                 const float* __restrict__ gamma,
                 const float* __restrict__ beta,
                 const float* __restrict__ rmean,
                 const float* __restrict__ rvar,
                 const float* __restrict__ bias1,
                 const float* __restrict__ alpha,
                 const float* __restrict__ bias2,
                 u64* __restrict__ Spk,
                 u64* __restrict__ wtab,      // [64][12]: [0..8]=bits, [9..10]=f32 consts
                 float* __restrict__ kc) {    // [9 classes][64]
    const int tid = threadIdx.x;
    const int lane = tid & 63;
    const int wv = tid >> 6;
    const int blk = blockIdx.x;

    if (blk < PBLK) {
        const int row = blk * 4 + wv;          // = b*56 + h
        const int b = row / HH;
        const int h = row - b * HH;
        const float* xp = x + ((size_t)(b * CH + lane)) * HW + h * WW;
        const float bz = bias0[lane];
        u64 mine = 0;
#pragma unroll
        for (int q = 0; q < 14; ++q) {
            float4 v = *(const float4*)(xp + q * 4);
            u64 m0 = __ballot(v.x + bz > 0.f);
            u64 m1 = __ballot(v.y + bz > 0.f);
            u64 m2 = __ballot(v.z + bz > 0.f);
            u64 m3 = __ballot(v.w + bz > 0.f);
            mine = (lane == q * 4 + 0) ? m0 : mine;
            mine = (lane == q * 4 + 1) ? m1 : mine;
            mine = (lane == q * 4 + 2) ? m2 : mine;
            mine = (lane == q * 4 + 3) ? m3 : mine;
        }
        u64* sp = Spk + (size_t)b * SIMG + (h + 1) * SROW;
        if (lane < WW)           sp[1 + lane] = mine;
        else if (lane == 56)     sp[0] = 0;
        else if (lane == 57)     sp[57] = 0;
        if (h == 0 && lane < 58)      Spk[(size_t)b * SIMG + lane] = 0;
        if (h == HH - 1 && lane < 58) Spk[(size_t)b * SIMG + 57 * SROW + lane] = 0;
    } else {
        __shared__ float red[4];
        const int p = blk - PBLK;
        const float* wp = w + p * 576;
        float s = 0.f;
        for (int i = tid; i < 576; i += 256) s += fabsf(wp[i]);
#pragma unroll
        for (int off = 32; off > 0; off >>= 1) s += __shfl_down(s, off);
        if (lane == 0) red[wv] = s;
        __syncthreads();

        if (wv == 0) {
            u64 m[9];
#pragma unroll
            for (int t = 0; t < 9; ++t) {
                m[t] = __ballot(wp[lane * 9 + t] > 0.f);   // bit c = sign(w[p][c][t])
                if (lane == 0) wtab[p * 12 + t] = m[t];
            }
            if (lane == 0) {
                float scale = (red[0] + red[1] + red[2] + red[3]) * (1.0f / 576.0f);
                float inv = gamma[p] * rsqrtf(rvar[p] + 1e-5f);
                float am = scale * inv;
                float bd = beta[p] - rmean[p] * inv + bias1[p];
                float pt[9];
#pragma unroll
                for (int t = 0; t < 9; ++t) pt[t] = (float)__popcll(m[t]);
                const float cL = pt[0] + pt[3] + pt[6];
                const float cR = pt[2] + pt[5] + pt[8];
                const float rT = pt[0] + pt[1] + pt[2];
                const float rB = pt[6] + pt[7] + pt[8];
                float Ci[3][3] = {
                    {0.f, cL,                 cR},
                    {rT,  rT + pt[3] + pt[6], rT + pt[5] + pt[8]},
                    {rB,  rB + pt[0] + pt[3], rB + pt[2] + pt[5]}};
                float nv[3][3] = {{9, 6, 6}, {6, 4, 4}, {6, 4, 4}};
#pragma unroll
                for (int wc = 0; wc < 3; ++wc)
#pragma unroll
                    for (int lc = 0; lc < 3; ++lc)
                        kc[(wc * 3 + lc) * 64 + p] =
                            fmaf(am, 64.f * nv[wc][lc] + 2.f * Ci[wc][lc], bd);
                float* wf = (float*)(wtab + p * 12 + 9);
                wf[0] = -2.f * am;
                wf[1] = alpha[p];
                wf[2] = bias2[p];
                wf[3] = 0.f;
            }
        }
    }
}

// Kernel 2: XNOR-popcount conv; weights via SGPR s_load (scalar pipe),
// A via unconditional global loads from zero-padded Spk (imm offsets),
// boundary corrections folded into kc class table (1 ds_read per p).
// 256 thr = 4 waves; wave = (row, p-half). Grid 1792 = 8*224 (XCD swizzle).
__global__ __launch_bounds__(256, 6)
void conv_kernel(const u64* __restrict__ Spk,
                 const u64* __restrict__ wtab,
                 const float* __restrict__ kc,
                 const float* __restrict__ x,
                 float* __restrict__ out) {
    __shared__ float kcsm[576];
    const int tid = threadIdx.x;
    for (int i = tid; i < 576; i += 256) kcsm[i] = kc[i];
    __syncthreads();

    const int bid = blockIdx.x;
    const int wg = (bid & 7) * 224 + (bid >> 3);      // bijective: 1792 = 8*224
    const int lane = tid & 63;
    const int wvu = __builtin_amdgcn_readfirstlane(tid >> 6);  // force uniform
    const int row = wg * 2 + (wvu & 1);
    const int ph = (wvu >> 1) << 5;                   // 0 or 32 (uniform)
    const int b = row / HH;
    const int h = row - b * HH;
    const int wl = min(lane, WW - 1);
    const bool active = lane < WW;

    // 9 tap words: one base, immediate offsets (pads make them unconditional)
    const u64* ap = Spk + (size_t)b * SIMG + (h + 1) * SROW + (wl + 1);
    u64 a0 = ap[-SROW - 1], a1 = ap[-SROW], a2 = ap[-SROW + 1];
    u64 a3 = ap[-1],        a4 = ap[0],     a5 = ap[1];
    u64 a6 = ap[SROW - 1],  a7 = ap[SROW],  a8 = ap[SROW + 1];

    const int wclass = (h == 0) ? 1 : (h == HH - 1) ? 2 : 0;
    const int lclass = (lane == 0) ? 1 : (lane == WW - 1) ? 2 : 0;
    const float* kp = kcsm + (wclass * 3 + lclass) * 64 + ph;

    size_t off = (size_t)b * CH * HW + (size_t)h * WW + wl + (size_t)ph * HW;
    const u64* wp = wtab + (size_t)ph * 12;           // uniform -> s_load

#pragma unroll 2
    for (int i = 0; i < 32; ++i) {
        u32 P = 0;
        u64 v;
        v = a0 ^ wp[0]; P += __popc((u32)v); P += __popc((u32)(v >> 32));
        v = a1 ^ wp[1]; P += __popc((u32)v); P += __popc((u32)(v >> 32));
        v = a2 ^ wp[2]; P += __popc((u32)v); P += __popc((u32)(v >> 32));
        v = a3 ^ wp[3]; P += __popc((u32)v); P += __popc((u32)(v >> 32));
        v = a4 ^ wp[4]; P += __popc((u32)v); P += __popc((u32)(v >> 32));
        v = a5 ^ wp[5]; P += __popc((u32)v); P += __popc((u32)(v >> 32));
        v = a6 ^ wp[6]; P += __popc((u32)v); P += __popc((u32)(v >> 32));
        v = a7 ^ wp[7]; P += __popc((u32)v); P += __popc((u32)(v >> 32));
        v = a8 ^ wp[8]; P += __popc((u32)v); P += __popc((u32)(v >> 32));

        const float* cf = (const float*)(wp + 9);     // {-2am, al, b2, 0} uniform
        const float k = kp[i];                        // 1 ds_read (broadcast-ish)
        const float res = x[off];
        float o = fmaf(cf[0], (float)P, k) + res;
        o = o >= 0.f ? o : cf[1] * o;
        o += cf[2];
        if (active) out[off] = o;

        off += HW;
        wp += 12;
    }
}

extern "C" void kernel_launch(void* const* d_in, const int* in_sizes, int n_in,
                              void* d_out, int out_size, void* d_ws, size_t ws_size,
                              hipStream_t stream) {
    const float* x     = (const float*)d_in[0];
    const float* bias0 = (const float*)d_in[1];
    const float* w     = (const float*)d_in[2];
    const float* gamma = (const float*)d_in[3];
    const float* beta  = (const float*)d_in[4];
    const float* rmean = (const float*)d_in[5];
    const float* rvar  = (const float*)d_in[6];
    const float* bias1 = (const float*)d_in[7];
    const float* alpha = (const float*)d_in[8];
    const float* bias2 = (const float*)d_in[9];
    float* out = (float*)d_out;

    char* ws = (char*)d_ws;
    u64* wtab = (u64*)ws;                  // 64*12*8 = 6,144 B
    float* kc = (float*)(ws + 6144);       // 9*64*4  = 2,304 B
    u64* Spk  = (u64*)(ws + 16384);        // 64*58*64*8 = 1,900,544 B

    pack_kernel<<<PBLK + 64, 256, 0, stream>>>(
        x, bias0, w, gamma, beta, rmean, rvar, bias1, alpha, bias2,
        Spk, wtab, kc);

    conv_kernel<<<(BATCH * HH) / 2, 256, 0, stream>>>(Spk, wtab, kc, x, out);
}